// Round 1
// baseline (15977.254 us; speedup 1.0000x reference)
//
#include <hip/hip_runtime.h>
#include <math.h>

#define BB 8
#define TT 1024
#define DM 512
#define ROWS (BB*TT)     // 8192
#define ROWS1 (BB*(TT-1))// 8184
#define GRU_G 64
#define GRU_S 8

__device__ __forceinline__ float sigm_(float v){ return 1.f/(1.f+expf(-v)); }

// ---------------- elementwise ----------------
__global__ __launch_bounds__(256) void delta_kernel(const float* __restrict__ x,
    const float* __restrict__ ts, float* __restrict__ delta)
{
  size_t i = (size_t)blockIdx.x*256 + threadIdx.x;
  int d = (int)(i & (DM-1));
  int r = (int)(i >> 9);
  int b = r / (TT-1), ii = r % (TT-1);
  float dt = ts[b*TT+ii+1] - ts[b*TT+ii];
  float x1 = x[((size_t)b*TT+ii+1)*DM + d];
  float x0 = x[((size_t)b*TT+ii)*DM + d];
  delta[i] = (x1 - x0) / dt;
}

template<int INIT, int WRITE_Y>
__global__ __launch_bounds__(256) void rk_kernel(float* __restrict__ acc,
    float* y, const float* __restrict__ delta,
    const float* __restrict__ f, const float* __restrict__ ts,
    float wa, float cy)
{
  size_t i = (size_t)blockIdx.x*256 + threadIdx.x;
  int r = (int)(i >> 9);
  int b = r / (TT-1), ii = r % (TT-1);
  float fv = f[i];
  float a = INIT ? 0.f : acc[i];
  acc[i] = a + wa*fv;
  if (WRITE_Y) {
    float dt = ts[b*TT+ii+1] - ts[b*TT+ii];
    y[i] = delta[i] + cy*dt*fv;
  }
}

__global__ __launch_bounds__(256) void states_kernel(const float* __restrict__ x,
    const float* __restrict__ ts, const float* __restrict__ acc,
    float* __restrict__ hin)
{
  size_t i = (size_t)blockIdx.x*256 + threadIdx.x;
  int d = (int)(i & (DM-1));
  int r = (int)(i >> 9);
  int b = r >> 10, t = r & (TT-1);
  float v = 0.f;
  if (t > 0) {
    int ii = t-1;
    float dt = ts[b*TT+ii+1] - ts[b*TT+ii];
    v = x[((size_t)b*TT+ii)*DM + d] + dt*(1.f/6.f)*acc[((size_t)b*(TT-1)+ii)*DM + d];
  }
  hin[i] = v;
}

__global__ __launch_bounds__(256) void timeenc_kernel(const float* __restrict__ x,
    const float* __restrict__ ts, const float* __restrict__ te_a,
    const float* __restrict__ te_b, float* __restrict__ z)
{
  size_t i = (size_t)blockIdx.x*256 + threadIdx.x;
  int d = (int)(i & (DM-1));
  int r = (int)(i >> 9);
  float t = ts[r];
  float tm;
  if (d & 1) {
    int j = d >> 1;                       // odd channels: ramp
    tm = t*te_a[j] + te_b[j];
  } else {
    int fi = d >> 2;                      // even: interleaved sin/cos
    float fr = expf(-(float)fi * 0.061606661f) * 1.5707964f; // exp(-i*ln(2500)/127)*pi/2
    float ph = t * fr;
    tm = ((d & 3) == 0) ? sinf(ph) : cosf(ph);
  }
  z[i] = x[i] + tm;
}

// ---------------- LayerNorm (block per row, D=512) ----------------
__global__ __launch_bounds__(256) void ln_kernel(const float* __restrict__ x,
    const float* __restrict__ w, const float* __restrict__ b,
    float* __restrict__ out)
{
  int row = blockIdx.x;
  int tid = threadIdx.x;
  const float* xr = x + (size_t)row*DM;
  float2 v = *(const float2*)(xr + tid*2);
  float s = v.x+v.y, sq = v.x*v.x + v.y*v.y;
  #pragma unroll
  for (int off=1; off<64; off<<=1){ s += __shfl_xor(s,off); sq += __shfl_xor(sq,off); }
  __shared__ float rs[4], rq[4];
  int wid = tid>>6;
  if ((tid&63)==0){ rs[wid]=s; rq[wid]=sq; }
  __syncthreads();
  s = rs[0]+rs[1]+rs[2]+rs[3];
  sq = rq[0]+rq[1]+rq[2]+rq[3];
  float mean = s*(1.f/DM);
  float var = sq*(1.f/DM) - mean*mean;
  float inv = rsqrtf(var + 1e-5f);
  float2 wv = *(const float2*)(w + tid*2);
  float2 bv = *(const float2*)(b + tid*2);
  float2 o;
  o.x = (v.x-mean)*inv*wv.x + bv.x;
  o.y = (v.y-mean)*inv*wv.y + bv.y;
  *(float2*)(out + (size_t)row*DM + tid*2) = o;
}

// ---------------- GEMM: C[m][n] = act(dot(A[m,:],W[n,:]) + bias[n]) (+res) ----------------
// A: MxK row-major, W: NxK row-major (i.e. C = A @ W^T). 128x64 tile, 8x4 micro.
template<int ACT>  // 0 none, 1 relu, 2 tanh
__global__ __launch_bounds__(256) void gemm_kernel(
    const float* __restrict__ A, const float* __restrict__ W,
    const float* __restrict__ bias, const float* res,
    float* C, int M, int N, int K, int ldc)
{
  __shared__ float As[16][132];   // [k][m]
  __shared__ float Ws[16][68];    // [k][n]
  const int bm = blockIdx.y * 128;
  const int bn = blockIdx.x * 64;
  const int tid = threadIdx.x;
  const int rg = tid >> 4;        // 0..15
  const int cg = tid & 15;        // 0..15
  float acc[8][4];
  #pragma unroll
  for (int i=0;i<8;i++){
    #pragma unroll
    for (int j=0;j<4;j++) acc[i][j]=0.f;
  }
  const int ar = tid >> 1;            // 0..127
  const int ak = (tid & 1) * 8;
  const int wr = tid >> 2;            // 0..63
  const int wk = (tid & 3) * 4;

  for (int k0 = 0; k0 < K; k0 += 16) {
    float4 a0 = {0,0,0,0}, a1 = {0,0,0,0};
    int gr = bm + ar;
    if (gr < M) {
      const float* p = A + (size_t)gr * K + k0 + ak;
      a0 = *(const float4*)p;
      a1 = *(const float4*)(p + 4);
    }
    As[ak+0][ar]=a0.x; As[ak+1][ar]=a0.y; As[ak+2][ar]=a0.z; As[ak+3][ar]=a0.w;
    As[ak+4][ar]=a1.x; As[ak+5][ar]=a1.y; As[ak+6][ar]=a1.z; As[ak+7][ar]=a1.w;
    {
      const float* p = W + (size_t)(bn + wr) * K + k0 + wk;
      float4 w4 = *(const float4*)p;
      Ws[wk+0][wr]=w4.x; Ws[wk+1][wr]=w4.y; Ws[wk+2][wr]=w4.z; Ws[wk+3][wr]=w4.w;
    }
    __syncthreads();
    #pragma unroll
    for (int kk=0;kk<16;kk++) {
      float4 av0 = *(const float4*)&As[kk][rg*8];
      float4 av1 = *(const float4*)&As[kk][rg*8+4];
      float4 wv  = *(const float4*)&Ws[kk][cg*4];
      float am[8] = {av0.x,av0.y,av0.z,av0.w,av1.x,av1.y,av1.z,av1.w};
      float wm[4] = {wv.x,wv.y,wv.z,wv.w};
      #pragma unroll
      for (int i=0;i<8;i++){
        #pragma unroll
        for (int j=0;j<4;j++) acc[i][j] = fmaf(am[i], wm[j], acc[i][j]);
      }
    }
    __syncthreads();
  }
  const int gn0 = bn + cg*4;
  float4 bv = *(const float4*)(bias + gn0);
  #pragma unroll
  for (int i=0;i<8;i++) {
    int gm = bm + rg*8 + i;
    if (gm >= M) continue;
    float4 v;
    v.x = acc[i][0]+bv.x; v.y = acc[i][1]+bv.y;
    v.z = acc[i][2]+bv.z; v.w = acc[i][3]+bv.w;
    if (ACT==1){ v.x=fmaxf(v.x,0.f); v.y=fmaxf(v.y,0.f); v.z=fmaxf(v.z,0.f); v.w=fmaxf(v.w,0.f); }
    if (ACT==2){ v.x=tanhf(v.x); v.y=tanhf(v.y); v.z=tanhf(v.z); v.w=tanhf(v.w); }
    if (res) {
      float4 r4 = *(const float4*)(res + (size_t)gm*ldc + gn0);
      v.x+=r4.x; v.y+=r4.y; v.z+=r4.z; v.w+=r4.w;
    }
    *(float4*)(C + (size_t)gm*ldc + gn0) = v;
  }
}

// ---------------- attention ----------------
// QKV: (B*T, 1536), Q cols [0,512), K [512,1024), V [1024,1536). heads 8 x 64.
// block: one (b,h) and 8 query rows. scores staged in LDS.
template<int CAUSAL>
__global__ __launch_bounds__(256) void attn_kernel(const float* __restrict__ QKV,
                                                   float* __restrict__ O)
{
  __shared__ float qt[8][68];
  __shared__ float kt[32][68];
  __shared__ float vt[32][68];
  __shared__ float sc[8][1028];
  const int bh = blockIdx.x;
  const int b = bh >> 3, h = bh & 7;
  const int q0 = blockIdx.y * 8;
  const int tid = threadIdx.x;
  const int qrow = tid >> 5;       // 0..7
  const int klane = tid & 31;      // 0..31
  const float* base = QKV + (size_t)b*TT*1536;
  for (int idx = tid; idx < 8*64; idx += 256) {
    int q = idx >> 6, d = idx & 63;
    qt[q][d] = base[(size_t)(q0+q)*1536 + h*64 + d];
  }
  const int nkt = CAUSAL ? (q0/32 + 1) : (TT/32);
  for (int t0 = 0; t0 < nkt; t0++) {
    __syncthreads();
    for (int idx = tid; idx < 32*64; idx += 256) {
      int kk = idx >> 6, d = idx & 63;
      kt[kk][d] = base[(size_t)(t0*32+kk)*1536 + 512 + h*64 + d];
    }
    __syncthreads();
    float s = 0.f;
    #pragma unroll
    for (int d = 0; d < 64; d += 4) {
      float4 qv = *(const float4*)&qt[qrow][d];
      float4 kv = *(const float4*)&kt[klane][d];
      s += qv.x*kv.x + qv.y*kv.y + qv.z*kv.z + qv.w*kv.w;
    }
    int kg = t0*32 + klane;
    s *= 0.125f;
    if (CAUSAL && kg > q0 + qrow) s = -1e30f;
    sc[qrow][kg] = s;
  }
  __syncthreads();
  const int nk = nkt*32;
  float mx = -1e30f;
  for (int k = klane; k < nk; k += 32) mx = fmaxf(mx, sc[qrow][k]);
  #pragma unroll
  for (int off=1; off<32; off<<=1) mx = fmaxf(mx, __shfl_xor(mx, off));
  float sum = 0.f;
  for (int k = klane; k < nk; k += 32) { float e = expf(sc[qrow][k]-mx); sc[qrow][k]=e; sum += e; }
  #pragma unroll
  for (int off=1; off<32; off<<=1) sum += __shfl_xor(sum, off);
  float inv = 1.f/sum;
  for (int k = klane; k < nk; k += 32) sc[qrow][k] *= inv;
  float o0=0.f, o1=0.f;
  for (int t0 = 0; t0 < nkt; t0++) {
    __syncthreads();
    for (int idx = tid; idx < 32*64; idx += 256) {
      int kk = idx >> 6, d = idx & 63;
      vt[kk][d] = base[(size_t)(t0*32+kk)*1536 + 1024 + h*64 + d];
    }
    __syncthreads();
    #pragma unroll
    for (int kk=0; kk<32; kk++) {
      float p = sc[qrow][t0*32+kk];
      o0 += p*vt[kk][klane];
      o1 += p*vt[kk][klane+32];
    }
  }
  float* op = O + (size_t)(b*TT + q0 + qrow)*DM + h*64 + klane;
  op[0]  = o0;
  op[32] = o1;
}

// ---------------- GRU scan: 64 blocks, each owns 8 hidden dims; global spin barrier ----------------
__global__ __launch_bounds__(256) void gru_scan_kernel(
    const float* __restrict__ gx,   // (B*T,1536) includes bih
    const float* __restrict__ whh,  // (1536,512)
    const float* __restrict__ bhh,  // (1536)
    float* __restrict__ Hs,         // (B*T,512)
    float* hbuf,                    // 2 * B*512
    int* cnt)
{
  extern __shared__ float smem[];
  float* wrp = smem;                       // [GRU_S][516]
  float* wzp = smem + GRU_S*516;
  float* wnp = smem + 2*GRU_S*516;
  float* hsp = smem + 3*GRU_S*516;         // [BB][512]
  float* red = smem + 3*GRU_S*516 + BB*512;// [4][GRU_S][3][BB]

  const int g = blockIdx.x, tid = threadIdx.x;
  const int j0 = g * GRU_S;
  for (int idx = tid; idx < GRU_S*512; idx += 256) {
    int jj = idx >> 9, k = idx & 511;
    wrp[jj*516+k] = whh[(size_t)(j0+jj)*512 + k];
    wzp[jj*516+k] = whh[(size_t)(512+j0+jj)*512 + k];
    wnp[jj*516+k] = whh[(size_t)(1024+j0+jj)*512 + k];
  }
  const int jj = tid & 7, q = tid >> 3;   // q 0..31, k-chunk of 16
  const int k0 = q * 16;
  const int lane = tid & 63, wid = tid >> 6;
  const int jjf = tid >> 3, bf = tid & 7; // for final 64 threads
  float bh0=0.f, bh1=0.f, bh2=0.f;
  if (tid < GRU_S*BB) {
    bh0 = bhh[j0+jjf]; bh1 = bhh[512+j0+jjf]; bh2 = bhh[1024+j0+jjf];
  }
  for (int t = 0; t < TT; t++) {
    float gx0=0.f, gx1=0.f, gx2=0.f;
    if (tid < GRU_S*BB) {
      const float* gxr = gx + ((size_t)bf*TT + t)*1536;
      int jg = j0 + jjf;
      gx0 = gxr[jg]; gx1 = gxr[512+jg]; gx2 = gxr[1024+jg];
    }
    if (t == 0) {
      for (int idx=tid; idx<BB*512; idx+=256) hsp[idx] = 0.f;
    } else {
      const float* src = hbuf + ((t&1)^1)*(BB*512);
      for (int idx=tid; idx<BB*512; idx+=256)
        hsp[idx] = __hip_atomic_load(src+idx, __ATOMIC_RELAXED, __HIP_MEMORY_SCOPE_AGENT);
    }
    __syncthreads();
    float ar[BB], az[BB], an[BB];
    #pragma unroll
    for (int b2=0;b2<BB;b2++){ ar[b2]=0.f; az[b2]=0.f; an[b2]=0.f; }
    #pragma unroll
    for (int k = 0; k < 16; k += 4) {
      float4 w1 = *(const float4*)&wrp[jj*516 + k0+k];
      float4 w2 = *(const float4*)&wzp[jj*516 + k0+k];
      float4 w3 = *(const float4*)&wnp[jj*516 + k0+k];
      #pragma unroll
      for (int b2=0;b2<BB;b2++) {
        float4 h4 = *(const float4*)&hsp[b2*512 + k0+k];
        ar[b2] += w1.x*h4.x + w1.y*h4.y + w1.z*h4.z + w1.w*h4.w;
        az[b2] += w2.x*h4.x + w2.y*h4.y + w2.z*h4.z + w2.w*h4.w;
        an[b2] += w3.x*h4.x + w3.y*h4.y + w3.z*h4.z + w3.w*h4.w;
      }
    }
    #pragma unroll
    for (int off=8; off<64; off<<=1) {
      #pragma unroll
      for (int b2=0;b2<BB;b2++) {
        ar[b2] += __shfl_xor(ar[b2], off);
        az[b2] += __shfl_xor(az[b2], off);
        an[b2] += __shfl_xor(an[b2], off);
      }
    }
    if (lane < GRU_S) {
      #pragma unroll
      for (int b2=0;b2<BB;b2++) {
        red[((wid*GRU_S + lane)*3 + 0)*BB + b2] = ar[b2];
        red[((wid*GRU_S + lane)*3 + 1)*BB + b2] = az[b2];
        red[((wid*GRU_S + lane)*3 + 2)*BB + b2] = an[b2];
      }
    }
    __syncthreads();
    if (tid < GRU_S*BB) {
      float sr=0.f, sz=0.f, sn=0.f;
      #pragma unroll
      for (int w=0;w<4;w++) {
        sr += red[((w*GRU_S + jjf)*3 + 0)*BB + bf];
        sz += red[((w*GRU_S + jjf)*3 + 1)*BB + bf];
        sn += red[((w*GRU_S + jjf)*3 + 2)*BB + bf];
      }
      int jg = j0 + jjf;
      float r  = sigm_(gx0 + sr + bh0);
      float z  = sigm_(gx1 + sz + bh1);
      float n  = tanhf(gx2 + r*(sn + bh2));
      float hold = hsp[bf*512 + jg];
      float hnew = (1.f-z)*n + z*hold;
      Hs[((size_t)bf*TT+t)*DM + jg] = hnew;
      __hip_atomic_store(hbuf + (t&1)*(BB*512) + bf*512 + jg, hnew,
                         __ATOMIC_RELAXED, __HIP_MEMORY_SCOPE_AGENT);
      __threadfence();
    }
    __syncthreads();
    if (tid == 0) {
      __hip_atomic_fetch_add(cnt, 1, __ATOMIC_ACQ_REL, __HIP_MEMORY_SCOPE_AGENT);
      const int target = GRU_G*(t+1);
      while (__hip_atomic_load(cnt, __ATOMIC_ACQUIRE, __HIP_MEMORY_SCOPE_AGENT) < target)
        __builtin_amdgcn_s_sleep(1);
    }
    __syncthreads();
  }
}

// ---------------- host ----------------
static void launch_gemm(int act, const float* A, const float* W, const float* bias,
                        const float* res, float* C, int M, int N, int K, int ldc,
                        hipStream_t stream)
{
  dim3 grid(N/64, (M+127)/128), blk(256);
  switch(act){
    case 1: gemm_kernel<1><<<grid,blk,0,stream>>>(A,W,bias,res,C,M,N,K,ldc); break;
    case 2: gemm_kernel<2><<<grid,blk,0,stream>>>(A,W,bias,res,C,M,N,K,ldc); break;
    default: gemm_kernel<0><<<grid,blk,0,stream>>>(A,W,bias,res,C,M,N,K,ldc); break;
  }
}

extern "C" void kernel_launch(void* const* d_in, const int* in_sizes, int n_in,
                              void* d_out, int out_size, void* d_ws, size_t ws_size,
                              hipStream_t stream)
{
  (void)in_sizes; (void)n_in; (void)out_size; (void)ws_size;
  const float* x       = (const float*)d_in[0];
  const float* ts      = (const float*)d_in[1];
  const float* ode_w1  = (const float*)d_in[2];
  const float* ode_b1  = (const float*)d_in[3];
  const float* ode_w2  = (const float*)d_in[4];
  const float* ode_b2  = (const float*)d_in[5];
  const float* gru_wih = (const float*)d_in[6];
  const float* gru_whh = (const float*)d_in[7];
  const float* gru_bih = (const float*)d_in[8];
  const float* gru_bhh = (const float*)d_in[9];
  const float* te_a    = (const float*)d_in[10];
  const float* te_b    = (const float*)d_in[11];
  const float* t_in_w  = (const float*)d_in[12];
  const float* t_in_b  = (const float*)d_in[13];
  const float* t_out_w = (const float*)d_in[14];
  const float* t_out_b = (const float*)d_in[15];
  const float* t_ln1_w = (const float*)d_in[16];
  const float* t_ln1_b = (const float*)d_in[17];
  const float* t_ln2_w = (const float*)d_in[18];
  const float* t_ln2_b = (const float*)d_in[19];
  const float* t_ff1_w = (const float*)d_in[20];
  const float* t_ff1_b = (const float*)d_in[21];
  const float* t_ff2_w = (const float*)d_in[22];
  const float* t_ff2_b = (const float*)d_in[23];
  const float* t_lnf_w = (const float*)d_in[24];
  const float* t_lnf_b = (const float*)d_in[25];
  const float* ca_in_w = (const float*)d_in[26];
  const float* ca_in_b = (const float*)d_in[27];
  const float* ca_out_w= (const float*)d_in[28];
  const float* ca_out_b= (const float*)d_in[29];
  const float* ca_lin_w= (const float*)d_in[30];
  const float* ca_lin_b= (const float*)d_in[31];
  const float* ca_ln_w = (const float*)d_in[32];
  const float* ca_ln_b = (const float*)d_in[33];

  float* ws = (float*)d_ws;
  const size_t SZ = (size_t)ROWS * DM;      // 4M floats = 16MB
  float* deltab = ws + 0*SZ;                // ODE delta; later attn O
  float* ycur   = ws + 1*SZ;
  float* fcur   = ws + 2*SZ;                // later cross-attn HB
  float* accb   = ws + 3*SZ;
  float* ff1    = ws + 0*SZ;                // aliases [0,4SZ) (ODE bufs dead by then)
  float* ybuf   = ws + 4*SZ;                // tanh tmp / LN y / cross AO
  float* hin    = ws + 5*SZ;                // H_in; later zf
  float* qkv    = ws + 6*SZ;                // 3*SZ: gx, later QKV
  float* hsb    = ws + 9*SZ;                // GRU output H (persists)
  float* zbuf   = ws + 10*SZ;               // transformer stream
  float* hbuf   = ws + 11*SZ;               // 2*4096 GRU h ping-pong
  int*   cnt    = (int*)(ws + 11*SZ + 2*BB*512);

  hipMemsetAsync(cnt, 0, 64, stream);

  // ---- ODE (RK4 over parallel states) ----
  delta_kernel<<<ROWS1*DM/256, 256, 0, stream>>>(x, ts, deltab);
  const float* yin = deltab;
  // stage 1: f1 = ode(delta)
  // stage s: t1 = tanh(y@W1^T+b1); f = t1@W2^T+b2; acc += w*f; y = delta + c*dt*f
  const float was[4] = {1.f, 2.f, 2.f, 1.f};
  const float cys[4] = {0.5f, 0.5f, 1.f, 0.f};
  for (int s4 = 0; s4 < 4; s4++) {
    launch_gemm(2, yin, ode_w1, ode_b1, nullptr, ybuf, ROWS1, 512, 512, 512, stream);
    launch_gemm(0, ybuf, ode_w2, ode_b2, nullptr, fcur, ROWS1, 512, 512, 512, stream);
    if (s4 == 0)
      rk_kernel<1,1><<<ROWS1*DM/256,256,0,stream>>>(accb, ycur, deltab, fcur, ts, was[s4], cys[s4]);
    else if (s4 < 3)
      rk_kernel<0,1><<<ROWS1*DM/256,256,0,stream>>>(accb, ycur, deltab, fcur, ts, was[s4], cys[s4]);
    else
      rk_kernel<0,0><<<ROWS1*DM/256,256,0,stream>>>(accb, nullptr, deltab, fcur, ts, was[s4], 0.f);
    yin = ycur;
  }
  states_kernel<<<ROWS*DM/256,256,0,stream>>>(x, ts, accb, hin);

  // ---- GRU ----
  launch_gemm(0, hin, gru_wih, gru_bih, nullptr, qkv, ROWS, 1536, 512, 1536, stream);
  const int gru_smem = (3*GRU_S*516 + BB*512 + 4*GRU_S*3*BB) * 4;
  gru_scan_kernel<<<GRU_G, 256, gru_smem, stream>>>(qkv, gru_whh, gru_bhh, hsb, hbuf, cnt);

  // ---- time encoding ----
  timeenc_kernel<<<ROWS*DM/256,256,0,stream>>>(x, ts, te_a, te_b, zbuf);

  // ---- transformer (2 layers, pre-norm, causal) ----
  for (int l = 0; l < 2; l++) {
    ln_kernel<<<ROWS,256,0,stream>>>(zbuf, t_ln1_w + l*512, t_ln1_b + l*512, ybuf);
    launch_gemm(0, ybuf, t_in_w + (size_t)l*1536*512, t_in_b + l*1536, nullptr, qkv, ROWS, 1536, 512, 1536, stream);
    attn_kernel<1><<<dim3(64, TT/8), 256, 0, stream>>>(qkv, deltab);
    launch_gemm(0, deltab, t_out_w + (size_t)l*512*512, t_out_b + l*512, zbuf, zbuf, ROWS, 512, 512, 512, stream);
    ln_kernel<<<ROWS,256,0,stream>>>(zbuf, t_ln2_w + l*512, t_ln2_b + l*512, ybuf);
    launch_gemm(1, ybuf, t_ff1_w + (size_t)l*2048*512, t_ff1_b + l*2048, nullptr, ff1, ROWS, 2048, 512, 2048, stream);
    launch_gemm(0, ff1, t_ff2_w + (size_t)l*512*2048, t_ff2_b + l*512, zbuf, zbuf, ROWS, 512, 2048, 512, stream);
  }
  ln_kernel<<<ROWS,256,0,stream>>>(zbuf, t_lnf_w, t_lnf_b, hin);   // hin = zf now

  // ---- cross attention: Q from Hs, K/V from zf ----
  launch_gemm(0, hsb, ca_in_w,            ca_in_b,       nullptr, qkv,       ROWS,  512, 512, 1536, stream);
  launch_gemm(0, hin, ca_in_w + 512*512,  ca_in_b + 512, nullptr, qkv + 512, ROWS, 1024, 512, 1536, stream);
  attn_kernel<0><<<dim3(64, TT/8), 256, 0, stream>>>(qkv, deltab);
  launch_gemm(0, deltab, ca_out_w, ca_out_b, nullptr, ybuf, ROWS, 512, 512, 512, stream);
  launch_gemm(0, ybuf, ca_lin_w, ca_lin_b, hsb, fcur, ROWS, 512, 512, 512, stream);
  ln_kernel<<<ROWS,256,0,stream>>>(fcur, ca_ln_w, ca_ln_b, (float*)d_out);
}